// Round 10
// baseline (516.838 us; speedup 1.0000x reference)
//
#include <hip/hip_runtime.h>
#include <hip/hip_bf16.h>
#include <math.h>

#define N_NODES   8192
#define NUM_E     49152
#define NUM_EDGES (NUM_E + N_NODES)   // 57344 (with self loops)
#define H_HEADS   6
#define C_DIM     512
#define HC        (H_HEADS * C_DIM)   // 3072
#define XLR       (2 * HC)            // 6144: xl | xr concatenated per row
#define N_FEAT    37
#define LRELU_SLOPE 0.2f
#define SELU_LAMBDA 1.0507009873554805f
#define SELU_ALPHA  1.6732632423543772f

typedef __bf16 bf16_t;
typedef bf16_t bf16x8 __attribute__((ext_vector_type(8)));
typedef float  f32x4  __attribute__((ext_vector_type(4)));
typedef float  f32x2  __attribute__((ext_vector_type(2)));

__device__ __forceinline__ int edge_src(const int* ei, int e) {
    return e < NUM_E ? ei[e] : (e - NUM_E);
}
__device__ __forceinline__ int edge_dst(const int* ei, int e) {
    return e < NUM_E ? ei[NUM_E + e] : (e - NUM_E);
}
__device__ __forceinline__ float selu_f(float v) {
    return v > 0.f ? SELU_LAMBDA * v : SELU_LAMBDA * SELU_ALPHA * (__expf(v) - 1.f);
}
__device__ __forceinline__ void gload_lds16(const void* g, void* l) {
    __builtin_amdgcn_global_load_lds((const __attribute__((address_space(1))) void*)g,
                                     (__attribute__((address_space(3))) void*)l, 16, 0, 0);
}

// 64-lane allreduce-add, bit-identical to the xor-butterfly but with the first
// 4 steps on the VALU (DPP) instead of ds_bpermute: quad_perm xor1/xor2, then
// half-mirror/mirror (valid because all lanes of a quad/oct are equal by then),
// ds_swizzle xor16, bpermute xor32. Frees the DS pipe + cuts chain latency ~2.5x.
__device__ __forceinline__ float bfly_add64(float s) {
    int t;
    t = __builtin_amdgcn_update_dpp(0, __float_as_int(s), 0xB1,  0xF, 0xF, true); // quad_perm [1,0,3,2]
    s += __int_as_float(t);
    t = __builtin_amdgcn_update_dpp(0, __float_as_int(s), 0x4E,  0xF, 0xF, true); // quad_perm [2,3,0,1]
    s += __int_as_float(t);
    t = __builtin_amdgcn_update_dpp(0, __float_as_int(s), 0x141, 0xF, 0xF, true); // row_half_mirror
    s += __int_as_float(t);
    t = __builtin_amdgcn_update_dpp(0, __float_as_int(s), 0x140, 0xF, 0xF, true); // row_mirror
    s += __int_as_float(t);
    s += __int_as_float(__builtin_amdgcn_ds_swizzle(__float_as_int(s), 0x401F)); // xor16
    s += __shfl_xor(s, 32);                                                      // xor32
    return s;
}

// ---------------- K1: hidden0, 4 nodes/block (R6 WIN: W reuse x4, kept)
__global__ __launch_bounds__(512) void k_hidden0(
    const float* __restrict__ x, const float* __restrict__ lf,
    const float* __restrict__ cf, const float* __restrict__ W,
    const float* __restrict__ b, bf16_t* __restrict__ hidden,
    float* __restrict__ coord)
{
    int n0 = blockIdx.x * 4;
    int c = threadIdx.x;
    __shared__ float f[4][N_FEAT];
    if (c < 4 * N_FEAT) {
        int m = c / N_FEAT, k = c - m * N_FEAT;
        int n = n0 + m;
        f[m][k] = (k < 5) ? x[n*7 + 2 + k]
                 : (k < 21 ? lf[n*16 + (k - 5)] : cf[n*16 + (k - 21)]);
    }
    if (c < 8) coord[n0*2 + c] = x[(n0 + (c >> 1))*7 + (c & 1)];
    __syncthreads();
    float a0 = b[c], a1 = a0, a2 = a0, a3 = a0;
    #pragma unroll
    for (int k = 0; k < N_FEAT; ++k) {
        float wv = W[k*C_DIM + c];
        a0 = fmaf(f[0][k], wv, a0);
        a1 = fmaf(f[1][k], wv, a1);
        a2 = fmaf(f[2][k], wv, a2);
        a3 = fmaf(f[3][k], wv, a3);
    }
    hidden[(size_t)(n0 + 0)*C_DIM + c] = (bf16_t)selu_f(a0);
    hidden[(size_t)(n0 + 1)*C_DIM + c] = (bf16_t)selu_f(a1);
    hidden[(size_t)(n0 + 2)*C_DIM + c] = (bf16_t)selu_f(a2);
    hidden[(size_t)(n0 + 3)*C_DIM + c] = (bf16_t)selu_f(a3);
}

// ---------------- weight transpose+convert
__global__ __launch_bounds__(256) void k_wt_transpose(const float* __restrict__ W,
                                                      bf16_t* __restrict__ WT)
{
    __shared__ float tile[32][33];
    int k0 = blockIdx.y * 32;
    int n0 = blockIdx.x * 32;
    int tx = threadIdx.x & 31, ty = threadIdx.x >> 5;
    #pragma unroll
    for (int i = 0; i < 4; ++i)
        tile[ty + i*8][tx] = W[(size_t)(k0 + 2 + ty + i*8) * HC + n0 + tx];
    __syncthreads();
    #pragma unroll
    for (int i = 0; i < 4; ++i)
        WT[(size_t)(n0 + ty + i*8) * C_DIM + k0 + tx] = (bf16_t)tile[tx][ty + i*8];
}

// ---------------- CSR build
__global__ void k_hist(const int* __restrict__ ei, int* __restrict__ counts) {
    int e = blockIdx.x * blockDim.x + threadIdx.x;
    if (e >= NUM_EDGES) return;
    atomicAdd(&counts[edge_dst(ei, e)], 1);
}

__global__ __launch_bounds__(256) void k_scan(const int* __restrict__ counts,
                                              int* __restrict__ row_ptr,
                                              int* __restrict__ cursor) {
    __shared__ int part[256];
    __shared__ int off[257];
    int t = threadIdx.x;
    int base = t * 32;
    int local[32];
    int s = 0;
    #pragma unroll
    for (int i = 0; i < 32; ++i) { local[i] = s; s += counts[base + i]; }
    part[t] = s;
    __syncthreads();
    if (t == 0) {
        off[0] = 0;
        for (int i = 0; i < 256; ++i) off[i+1] = off[i] + part[i];
    }
    __syncthreads();
    int o = off[t];
    #pragma unroll
    for (int i = 0; i < 32; ++i) {
        int v = o + local[i];
        row_ptr[base + i] = v;
        cursor[base + i]  = v;
    }
    if (t == 255) row_ptr[N_NODES] = off[256];
}

__global__ void k_scatter(const int* __restrict__ ei, int* __restrict__ cursor,
                          int* __restrict__ csr_src) {
    int e = blockIdx.x * blockDim.x + threadIdx.x;
    if (e >= NUM_EDGES) return;
    int pos = atomicAdd(&cursor[edge_dst(ei, e)], 1);
    csr_src[pos] = edge_src(ei, e);
}

// ---------------- bf16 MFMA GEMM, 256x256, BK=64, 8-wave, 4-phase counted-vmcnt.
// R9 schedule kept (GEMM dispatches all <75us, absmax clean): race-free
// publication (reads of tile t only after the barrier at which every wave's
// vmcnt confirmed t's staging); plain-IR ds_reads so the compiler emits minimal
// fine-grained lgkm waits; stageB at ph1/ph2 for vmcnt headroom.
#define BM 256
#define BN 256
#define BK 64
#define NT (C_DIM / BK)                      // 8
#define NBX (XLR / BN)                       // 24
#define NWG ((N_NODES / BM) * NBX)           // 768

__global__ __launch_bounds__(512, 2) void k_gemm_bf16(
    const bf16_t* __restrict__ A,
    const bf16_t* __restrict__ BT,
    const float*  __restrict__ Wl,
    const float*  __restrict__ Wr,
    const float*  __restrict__ coord,
    bf16_t* __restrict__ out)
{
    __shared__ __align__(1024) char smem[131072];   // A: 64KB  B: 64KB
    char* sA = smem;
    char* sB = smem + 65536;

    const int tid  = threadIdx.x;
    const int wave = tid >> 6;
    const int lane = tid & 63;
    const int wm   = wave >> 2;     // 0..1
    const int wn   = wave & 3;      // 0..3

    int bid = blockIdx.y * gridDim.x + blockIdx.x;
    bid = (bid & 7) * (NWG / 8) + (bid >> 3);
    const int rowBase = (bid / NBX) * BM;
    const int colBase = (bid % NBX) * BN;

    const int rtid = tid >> 3;
    const int csw  = ((tid & 7) * 8) ^ (((tid >> 3) & 7) << 3);
    const bf16_t* pA = A  + (size_t)(rowBase + rtid) * C_DIM + csw;
    const bf16_t* pB = BT + (size_t)(colBase + rtid) * C_DIM + csw;

    auto stageA = [&](int t, int h) {
        char* l = sA + ((t & 1) << 15) + (h << 14) + (wave << 10);
        const bf16_t* g = pA + (size_t)(h * 128) * C_DIM + t * BK;
        gload_lds16(g,              l);
        gload_lds16(g + 64 * C_DIM, l + 8192);
    };
    auto stageB = [&](int t, int h) {
        char* l = sB + ((t & 1) << 15) + (h << 14) + (wave << 10);
        const bf16_t* g = pB + (size_t)(h * 128) * C_DIM + t * BK;
        gload_lds16(g,              l);
        gload_lds16(g + 64 * C_DIM, l + 8192);
    };

    // prologue: tile0 complete + tile1 B-halves (12 loads)
    stageB(0, 0); stageB(0, 1); stageA(0, 0); stageA(0, 1);
    stageB(1, 0); stageB(1, 1);
    __builtin_amdgcn_sched_barrier(0);
    asm volatile("s_waitcnt vmcnt(4)" ::: "memory");   // tile0's 8 loads landed (own)
    __builtin_amdgcn_sched_barrier(0);
    asm volatile("s_barrier" ::: "memory");            // -> landed for ALL waves
    __builtin_amdgcn_sched_barrier(0);

    const int kb  = (lane >> 4) << 4;
    const int sw  = (lane & 7) << 4;
    const int xt0 = kb ^ sw;
    const int xt1 = (64 | kb) ^ sw;
    const int aRowOff = (wm * 128 + (lane & 15)) * 128;
    const int bRowOff = (wn * 64  + (lane & 15)) * 128;

    f32x4 acc[8][4] = {};

    #pragma unroll 2
    for (int t = 0; t < NT; ++t) {
        const char* aP = sA + ((t & 1) << 15) + aRowOff;
        const char* bP = sB + ((t & 1) << 15) + bRowOff;
        bf16x8 bfv[4][2];
        bf16x8 af[2][2][2];   // [parity][frag-in-pair][ks]

        // ================= ph0: MFMA A01; reads A01+B+A23; stage A(t+1,0)
        if (t + 1 < NT) stageA(t + 1, 0);
        af[0][0][0] = *(const bf16x8*)(aP + 0*2048 + xt0);
        af[0][0][1] = *(const bf16x8*)(aP + 0*2048 + xt1);
        af[0][1][0] = *(const bf16x8*)(aP + 1*2048 + xt0);
        af[0][1][1] = *(const bf16x8*)(aP + 1*2048 + xt1);
        #pragma unroll
        for (int nf = 0; nf < 4; ++nf) {
            bfv[nf][0] = *(const bf16x8*)(bP + nf * 2048 + xt0);
            bfv[nf][1] = *(const bf16x8*)(bP + nf * 2048 + xt1);
        }
        af[1][0][0] = *(const bf16x8*)(aP + 2*2048 + xt0);
        af[1][0][1] = *(const bf16x8*)(aP + 2*2048 + xt1);
        af[1][1][0] = *(const bf16x8*)(aP + 3*2048 + xt0);
        af[1][1][1] = *(const bf16x8*)(aP + 3*2048 + xt1);
        __builtin_amdgcn_s_setprio(1);
        #pragma unroll
        for (int nf = 0; nf < 4; ++nf) {
            acc[0][nf] = __builtin_amdgcn_mfma_f32_16x16x32_bf16(af[0][0][0], bfv[nf][0], acc[0][nf], 0, 0, 0);
            acc[1][nf] = __builtin_amdgcn_mfma_f32_16x16x32_bf16(af[0][1][0], bfv[nf][0], acc[1][nf], 0, 0, 0);
        }
        #pragma unroll
        for (int nf = 0; nf < 4; ++nf) {
            acc[0][nf] = __builtin_amdgcn_mfma_f32_16x16x32_bf16(af[0][0][1], bfv[nf][1], acc[0][nf], 0, 0, 0);
            acc[1][nf] = __builtin_amdgcn_mfma_f32_16x16x32_bf16(af[0][1][1], bfv[nf][1], acc[1][nf], 0, 0, 0);
        }
        __builtin_amdgcn_s_setprio(0);
        __builtin_amdgcn_sched_barrier(0);
        asm volatile("s_barrier" ::: "memory");
        __builtin_amdgcn_sched_barrier(0);

        // ================= ph1: MFMA A23; reads A45; stage A(t+1,1), B(t+2,0)
        if (t + 1 < NT) stageA(t + 1, 1);
        if (t + 2 < NT) stageB(t + 2, 0);
        af[0][0][0] = *(const bf16x8*)(aP + 4*2048 + xt0);
        af[0][0][1] = *(const bf16x8*)(aP + 4*2048 + xt1);
        af[0][1][0] = *(const bf16x8*)(aP + 5*2048 + xt0);
        af[0][1][1] = *(const bf16x8*)(aP + 5*2048 + xt1);
        __builtin_amdgcn_s_setprio(1);
        #pragma unroll
        for (int nf = 0; nf < 4; ++nf) {
            acc[2][nf] = __builtin_amdgcn_mfma_f32_16x16x32_bf16(af[1][0][0], bfv[nf][0], acc[2][nf], 0, 0, 0);
            acc[3][nf] = __builtin_amdgcn_mfma_f32_16x16x32_bf16(af[1][1][0], bfv[nf][0], acc[3][nf], 0, 0, 0);
        }
        #pragma unroll
        for (int nf = 0; nf < 4; ++nf) {
            acc[2][nf] = __builtin_amdgcn_mfma_f32_16x16x32_bf16(af[1][0][1], bfv[nf][1], acc[2][nf], 0, 0, 0);
            acc[3][nf] = __builtin_amdgcn_mfma_f32_16x16x32_bf16(af[1][1][1], bfv[nf][1], acc[3][nf], 0, 0, 0);
        }
        __builtin_amdgcn_s_setprio(0);
        __builtin_amdgcn_sched_barrier(0);
        asm volatile("s_barrier" ::: "memory");
        __builtin_amdgcn_sched_barrier(0);

        // ================= ph2: MFMA A45; reads A67; stage B(t+2,1)
        if (t + 2 < NT) stageB(t + 2, 1);
        af[1][0][0] = *(const bf16x8*)(aP + 6*2048 + xt0);
        af[1][0][1] = *(const bf16x8*)(aP + 6*2048 + xt1);
        af[1][1][0] = *(const bf16x8*)(aP + 7*2048 + xt0);
        af[1][1][1] = *(const bf16x8*)(aP + 7*2048 + xt1);
        __builtin_amdgcn_s_setprio(1);
        #pragma unroll
        for (int nf = 0; nf < 4; ++nf) {
            acc[4][nf] = __builtin_amdgcn_mfma_f32_16x16x32_bf16(af[0][0][0], bfv[nf][0], acc[4][nf], 0, 0, 0);
            acc[5][nf] = __builtin_amdgcn_mfma_f32_16x16x32_bf16(af[0][1][0], bfv[nf][0], acc[5][nf], 0, 0, 0);
        }
        #pragma unroll
        for (int nf = 0; nf < 4; ++nf) {
            acc[4][nf] = __builtin_amdgcn_mfma_f32_16x16x32_bf16(af[0][0][1], bfv[nf][1], acc[4][nf], 0, 0, 0);
            acc[5][nf] = __builtin_amdgcn_mfma_f32_16x16x32_bf16(af[0][1][1], bfv[nf][1], acc[5][nf], 0, 0, 0);
        }
        __builtin_amdgcn_s_setprio(0);
        __builtin_amdgcn_sched_barrier(0);
        asm volatile("s_barrier" ::: "memory");
        __builtin_amdgcn_sched_barrier(0);

        // ================= ph3: vmcnt publication; MFMA A67
        __builtin_amdgcn_sched_barrier(0);
        if (t < NT - 2)       asm volatile("s_waitcnt vmcnt(4)" ::: "memory");
        else if (t == NT - 2) asm volatile("s_waitcnt vmcnt(0)" ::: "memory");
        __builtin_amdgcn_sched_barrier(0);
        __builtin_amdgcn_s_setprio(1);
        #pragma unroll
        for (int nf = 0; nf < 4; ++nf) {
            acc[6][nf] = __builtin_amdgcn_mfma_f32_16x16x32_bf16(af[1][0][0], bfv[nf][0], acc[6][nf], 0, 0, 0);
            acc[7][nf] = __builtin_amdgcn_mfma_f32_16x16x32_bf16(af[1][1][0], bfv[nf][0], acc[7][nf], 0, 0, 0);
        }
        #pragma unroll
        for (int nf = 0; nf < 4; ++nf) {
            acc[6][nf] = __builtin_amdgcn_mfma_f32_16x16x32_bf16(af[1][0][1], bfv[nf][1], acc[6][nf], 0, 0, 0);
            acc[7][nf] = __builtin_amdgcn_mfma_f32_16x16x32_bf16(af[1][1][1], bfv[nf][1], acc[7][nf], 0, 0, 0);
        }
        __builtin_amdgcn_s_setprio(0);
        __builtin_amdgcn_sched_barrier(0);
        asm volatile("s_barrier" ::: "memory");   // publishes tile t+1
        __builtin_amdgcn_sched_barrier(0);
    }

    // ---- epilogue: fused coord contribution (unchanged)
    const float* Wtop = (colBase < HC) ? Wl : Wr;
    const int coff = (colBase < HC) ? 0 : HC;
    const int ccol  = lane & 15;
    const int crow4 = (lane >> 4) * 4;

    float wv0[4], wv1[4];
    #pragma unroll
    for (int nf = 0; nf < 4; ++nf) {
        int wcol = colBase + wn*64 + nf*16 + ccol - coff;
        wv0[nf] = Wtop[wcol];
        wv1[nf] = Wtop[HC + wcol];
    }
    #pragma unroll
    for (int mf = 0; mf < 8; ++mf) {
        #pragma unroll
        for (int r = 0; r < 4; ++r) {
            int row = rowBase + wm*128 + mf*16 + crow4 + r;
            float c0 = coord[row*2 + 0], c1 = coord[row*2 + 1];
            size_t rb = (size_t)row * XLR;
            #pragma unroll
            for (int nf = 0; nf < 4; ++nf) {
                int col = colBase + wn*64 + nf*16 + ccol;
                out[rb + col] = (bf16_t)(acc[mf][nf][r] + c0 * wv0[nf] + c1 * wv1[nf]);
            }
        }
    }
}

// ---------------- fused attention — R1 dataflow; R10: DPP butterfly reduction
// (bit-identical sums, 4/6 steps moved off the DS pipe onto VALU)
#define MAX_DEG 128
__global__ __launch_bounds__(384, 8) void k_attn_agg(
    const bf16_t* __restrict__ xlr,
    const int* __restrict__ row_ptr, const int* __restrict__ csr_src,
    const float* __restrict__ att,
    const float* __restrict__ gat_bias, const float* __restrict__ W_coord,
    const float* __restrict__ b_coord, const float* __restrict__ coord_in,
    bf16_t* __restrict__ hidden, float* __restrict__ coord_out)
{
    int n = blockIdx.x;
    int tid = threadIdx.x;
    int h = tid >> 6, lane = tid & 63;
    __shared__ int   s_src[MAX_DEG];
    __shared__ float s_acc[HC];        // 12 KB
    __shared__ float s_red[12];

    int beg = row_ptr[n];
    int deg = min(row_ptr[n + 1] - beg, MAX_DEG);
    for (int j = tid; j < deg; j += 384) s_src[j] = csr_src[beg + j];
    __syncthreads();

    size_t off = (size_t)h * C_DIM + lane * 8;
    bf16x8 xrv = *(const bf16x8*)(xlr + (size_t)n * XLR + HC + off);
    f32x2 xr2[4], at2[4], ac2[4] = {};
    #pragma unroll
    for (int i = 0; i < 4; ++i) {
        xr2[i] = f32x2{(float)xrv[2*i], (float)xrv[2*i+1]};
        at2[i] = f32x2{att[off + 2*i], att[off + 2*i + 1]};
    }

    float l = 0.f;
    int j = 0;
    for (; j + 2 <= deg; j += 2) {
        bf16x8 xa = *(const bf16x8*)(xlr + (size_t)s_src[j]     * XLR + off);
        bf16x8 xb = *(const bf16x8*)(xlr + (size_t)s_src[j + 1] * XLR + off);
        f32x2 xla[4], xlb[4];
        #pragma unroll
        for (int i = 0; i < 4; ++i) {
            xla[i] = f32x2{(float)xa[2*i], (float)xa[2*i+1]};
            xlb[i] = f32x2{(float)xb[2*i], (float)xb[2*i+1]};
        }
        f32x2 sa = {0.f, 0.f}, sb = {0.f, 0.f};
        #pragma unroll
        for (int i = 0; i < 4; ++i) {
            f32x2 va = xla[i] + xr2[i];
            f32x2 vb = xlb[i] + xr2[i];
            sa += __builtin_elementwise_max(va, va * LRELU_SLOPE) * at2[i];
            sb += __builtin_elementwise_max(vb, vb * LRELU_SLOPE) * at2[i];
        }
        float suma = bfly_add64(sa.x + sa.y);
        float sumb = bfly_add64(sb.x + sb.y);
        float aa = __expf(suma), ab = __expf(sumb);
        l += aa + ab;
        #pragma unroll
        for (int i = 0; i < 4; ++i) ac2[i] += aa * xla[i] + ab * xlb[i];
    }
    if (j < deg) {
        bf16x8 xa = *(const bf16x8*)(xlr + (size_t)s_src[j] * XLR + off);
        f32x2 xla[4];
        #pragma unroll
        for (int i = 0; i < 4; ++i) xla[i] = f32x2{(float)xa[2*i], (float)xa[2*i+1]};
        f32x2 sa = {0.f, 0.f};
        #pragma unroll
        for (int i = 0; i < 4; ++i) {
            f32x2 va = xla[i] + xr2[i];
            sa += __builtin_elementwise_max(va, va * LRELU_SLOPE) * at2[i];
        }
        float suma = bfly_add64(sa.x + sa.y);
        float aa = __expf(suma);
        l += aa;
        #pragma unroll
        for (int i = 0; i < 4; ++i) ac2[i] += aa * xla[i];
    }

    float invl = 1.f / (l + 1e-16f) * (1.f / 6.f);   // fold head-mean
    #pragma unroll
    for (int i = 0; i < 4; ++i) {
        s_acc[off + 2*i]     = ac2[i].x * invl;
        s_acc[off + 2*i + 1] = ac2[i].y * invl;
    }
    __syncthreads();

    float p0 = 0.f, p1 = 0.f;
    for (int c = tid; c < C_DIM; c += 384) {
        float s = 0.f;
        #pragma unroll
        for (int hh = 0; hh < H_HEADS; ++hh) s += s_acc[hh * C_DIM + c];
        float hv = selu_f(s + gat_bias[c]);
        hidden[n * C_DIM + c] = (bf16_t)hv;
        p0 = fmaf(hv, W_coord[c * 2 + 0], p0);
        p1 = fmaf(hv, W_coord[c * 2 + 1], p1);
    }
    #pragma unroll
    for (int o = 32; o > 0; o >>= 1) { p0 += __shfl_down(p0, o); p1 += __shfl_down(p1, o); }
    if (lane == 0) { s_red[h * 2] = p0; s_red[h * 2 + 1] = p1; }
    __syncthreads();
    if (tid == 0) {
        float o0 = b_coord[0], o1 = b_coord[1];
        #pragma unroll
        for (int w = 0; w < H_HEADS; ++w) { o0 += s_red[w * 2]; o1 += s_red[w * 2 + 1]; }
        float cx = coord_in[n * 2 + 0], cy = coord_in[n * 2 + 1];
        float ox = (cx == 0.0f) ? 0.f : ((cx == 1.0f) ? 1.f : o0);
        float oy = (cy == 1.0f) ? 1.f : ((cy == 0.0f) ? 0.f : o1);
        coord_out[n * 2 + 0] = ox;
        coord_out[n * 2 + 1] = oy;
    }
}

extern "C" void kernel_launch(void* const* d_in, const int* in_sizes, int n_in,
                              void* d_out, int out_size, void* d_ws, size_t ws_size,
                              hipStream_t stream)
{
    const float* x       = (const float*)d_in[0];
    const float* lf      = (const float*)d_in[1];
    const float* cf      = (const float*)d_in[2];
    const float* W_lin   = (const float*)d_in[3];
    const float* b_lin   = (const float*)d_in[4];
    const float* Wl      = (const float*)d_in[5];
    const float* Wr      = (const float*)d_in[6];
    const float* att     = (const float*)d_in[7];
    const float* gbias   = (const float*)d_in[8];
    const float* W_coord = (const float*)d_in[9];
    const float* b_coord = (const float*)d_in[10];
    const int*   ei      = (const int*)d_in[11];

    char* w = (char*)d_ws;
    auto alloc = [&](size_t bytes) { char* p = w; w += (bytes + 255) & ~255ull; return p; };
    bf16_t*   hidden  = (bf16_t*)alloc((size_t)N_NODES * C_DIM * 2);
    bf16_t*   WT      = (bf16_t*)alloc((size_t)XLR * C_DIM * 2);
    bf16_t*   xlr     = (bf16_t*)alloc((size_t)N_NODES * XLR * 2);
    int*      counts  = (int*)alloc((size_t)N_NODES * 4);
    int*      row_ptr = (int*)alloc((size_t)(N_NODES + 1) * 4);
    int*      cursor  = (int*)alloc((size_t)N_NODES * 4);
    int*      csr_src = (int*)alloc((size_t)NUM_EDGES * 4);
    float*    cA      = (float*)alloc((size_t)N_NODES * 2 * 4);
    float*    cB      = (float*)alloc((size_t)N_NODES * 2 * 4);

    hipMemsetAsync(counts, 0, (size_t)N_NODES * 4, stream);
    k_hidden0<<<N_NODES / 4, 512, 0, stream>>>(x, lf, cf, W_lin, b_lin, hidden, cA);
    {
        dim3 tg(HC / 32, C_DIM / 32);
        k_wt_transpose<<<tg, 256, 0, stream>>>(Wl, WT);
        k_wt_transpose<<<tg, 256, 0, stream>>>(Wr, WT + (size_t)HC * C_DIM);
    }
    k_hist<<<(NUM_EDGES + 255) / 256, 256, 0, stream>>>(ei, counts);
    k_scan<<<1, 256, 0, stream>>>(counts, row_ptr, cursor);
    k_scatter<<<(NUM_EDGES + 255) / 256, 256, 0, stream>>>(ei, cursor, csr_src);

    float* cin = cA;
    for (int it = 0; it < 3; ++it) {
        float* cout = (it == 2) ? (float*)d_out : ((it == 0) ? cB : cA);
        dim3 g(NBX, N_NODES / BM);
        k_gemm_bf16<<<g, 512, 0, stream>>>(hidden, WT, Wl, Wr, cin, xlr);
        k_attn_agg<<<N_NODES, 384, 0, stream>>>(xlr, row_ptr, csr_src, att,
                                                gbias, W_coord, b_coord, cin, hidden, cout);
        cin = cout;
    }
}

// Round 11
// 484.087 us; speedup vs baseline: 1.0677x; 1.0677x over previous
//
#include <hip/hip_runtime.h>
#include <hip/hip_bf16.h>
#include <math.h>

#define N_NODES   8192
#define NUM_E     49152
#define NUM_EDGES (NUM_E + N_NODES)   // 57344 (with self loops)
#define H_HEADS   6
#define C_DIM     512
#define HC        (H_HEADS * C_DIM)   // 3072
#define XLR       (2 * HC)            // 6144: xl | xr concatenated per row
#define N_FEAT    37
#define LRELU_SLOPE 0.2f
#define SELU_LAMBDA 1.0507009873554805f
#define SELU_ALPHA  1.6732632423543772f

typedef __bf16 bf16_t;
typedef bf16_t bf16x8 __attribute__((ext_vector_type(8)));
typedef float  f32x4  __attribute__((ext_vector_type(4)));
typedef float  f32x2  __attribute__((ext_vector_type(2)));

__device__ __forceinline__ int edge_src(const int* ei, int e) {
    return e < NUM_E ? ei[e] : (e - NUM_E);
}
__device__ __forceinline__ int edge_dst(const int* ei, int e) {
    return e < NUM_E ? ei[NUM_E + e] : (e - NUM_E);
}
__device__ __forceinline__ float selu_f(float v) {
    return v > 0.f ? SELU_LAMBDA * v : SELU_LAMBDA * SELU_ALPHA * (__expf(v) - 1.f);
}
__device__ __forceinline__ void gload_lds16(const void* g, void* l) {
    __builtin_amdgcn_global_load_lds((const __attribute__((address_space(1))) void*)g,
                                     (__attribute__((address_space(3))) void*)l, 16, 0, 0);
}

// 64-lane allreduce-add, bit-identical to the xor-butterfly but with the first
// 4 steps on the VALU (DPP) instead of ds_bpermute (R10 WIN: attn 75 -> <70).
__device__ __forceinline__ float bfly_add64(float s) {
    int t;
    t = __builtin_amdgcn_update_dpp(0, __float_as_int(s), 0xB1,  0xF, 0xF, true); // quad_perm [1,0,3,2]
    s += __int_as_float(t);
    t = __builtin_amdgcn_update_dpp(0, __float_as_int(s), 0x4E,  0xF, 0xF, true); // quad_perm [2,3,0,1]
    s += __int_as_float(t);
    t = __builtin_amdgcn_update_dpp(0, __float_as_int(s), 0x141, 0xF, 0xF, true); // row_half_mirror
    s += __int_as_float(t);
    t = __builtin_amdgcn_update_dpp(0, __float_as_int(s), 0x140, 0xF, 0xF, true); // row_mirror
    s += __int_as_float(t);
    s += __int_as_float(__builtin_amdgcn_ds_swizzle(__float_as_int(s), 0x401F)); // xor16
    s += __shfl_xor(s, 32);                                                      // xor32
    return s;
}

// ---------------- K1: hidden0, 4 nodes/block (R6 WIN: W reuse x4, kept)
__global__ __launch_bounds__(512) void k_hidden0(
    const float* __restrict__ x, const float* __restrict__ lf,
    const float* __restrict__ cf, const float* __restrict__ W,
    const float* __restrict__ b, bf16_t* __restrict__ hidden,
    float* __restrict__ coord)
{
    int n0 = blockIdx.x * 4;
    int c = threadIdx.x;
    __shared__ float f[4][N_FEAT];
    if (c < 4 * N_FEAT) {
        int m = c / N_FEAT, k = c - m * N_FEAT;
        int n = n0 + m;
        f[m][k] = (k < 5) ? x[n*7 + 2 + k]
                 : (k < 21 ? lf[n*16 + (k - 5)] : cf[n*16 + (k - 21)]);
    }
    if (c < 8) coord[n0*2 + c] = x[(n0 + (c >> 1))*7 + (c & 1)];
    __syncthreads();
    float a0 = b[c], a1 = a0, a2 = a0, a3 = a0;
    #pragma unroll
    for (int k = 0; k < N_FEAT; ++k) {
        float wv = W[k*C_DIM + c];
        a0 = fmaf(f[0][k], wv, a0);
        a1 = fmaf(f[1][k], wv, a1);
        a2 = fmaf(f[2][k], wv, a2);
        a3 = fmaf(f[3][k], wv, a3);
    }
    hidden[(size_t)(n0 + 0)*C_DIM + c] = (bf16_t)selu_f(a0);
    hidden[(size_t)(n0 + 1)*C_DIM + c] = (bf16_t)selu_f(a1);
    hidden[(size_t)(n0 + 2)*C_DIM + c] = (bf16_t)selu_f(a2);
    hidden[(size_t)(n0 + 3)*C_DIM + c] = (bf16_t)selu_f(a3);
}

// ---------------- weight transpose+convert
__global__ __launch_bounds__(256) void k_wt_transpose(const float* __restrict__ W,
                                                      bf16_t* __restrict__ WT)
{
    __shared__ float tile[32][33];
    int k0 = blockIdx.y * 32;
    int n0 = blockIdx.x * 32;
    int tx = threadIdx.x & 31, ty = threadIdx.x >> 5;
    #pragma unroll
    for (int i = 0; i < 4; ++i)
        tile[ty + i*8][tx] = W[(size_t)(k0 + 2 + ty + i*8) * HC + n0 + tx];
    __syncthreads();
    #pragma unroll
    for (int i = 0; i < 4; ++i)
        WT[(size_t)(n0 + ty + i*8) * C_DIM + k0 + tx] = (bf16_t)tile[tx][ty + i*8];
}

// ---------------- CSR build
__global__ void k_hist(const int* __restrict__ ei, int* __restrict__ counts) {
    int e = blockIdx.x * blockDim.x + threadIdx.x;
    if (e >= NUM_EDGES) return;
    atomicAdd(&counts[edge_dst(ei, e)], 1);
}

__global__ __launch_bounds__(256) void k_scan(const int* __restrict__ counts,
                                              int* __restrict__ row_ptr,
                                              int* __restrict__ cursor) {
    __shared__ int part[256];
    __shared__ int off[257];
    int t = threadIdx.x;
    int base = t * 32;
    int local[32];
    int s = 0;
    #pragma unroll
    for (int i = 0; i < 32; ++i) { local[i] = s; s += counts[base + i]; }
    part[t] = s;
    __syncthreads();
    if (t == 0) {
        off[0] = 0;
        for (int i = 0; i < 256; ++i) off[i+1] = off[i] + part[i];
    }
    __syncthreads();
    int o = off[t];
    #pragma unroll
    for (int i = 0; i < 32; ++i) {
        int v = o + local[i];
        row_ptr[base + i] = v;
        cursor[base + i]  = v;
    }
    if (t == 255) row_ptr[N_NODES] = off[256];
}

__global__ void k_scatter(const int* __restrict__ ei, int* __restrict__ cursor,
                          int* __restrict__ csr_src) {
    int e = blockIdx.x * blockDim.x + threadIdx.x;
    if (e >= NUM_EDGES) return;
    int pos = atomicAdd(&cursor[edge_dst(ei, e)], 1);
    csr_src[pos] = edge_src(ei, e);
}

// ---------------- bf16 MFMA GEMM, 256x256, BK=64, 8-wave.
// R11: 2 superphases per K-tile (was 4 phases) — halves barrier count (32->16
// per block; each barrier exposes full skew at 2 waves/SIMD) and doubles the
// scheduler's window for hiding ds_read latency under MFMA.
// SP0: stage A(t+1) both halves; read A rows0-3 + all B; 32 MFMA; barrier.
// SP1: stage B(t+2) both halves; read A rows4-7; 32 MFMA; vmcnt; barrier.
// vmcnt trace at t.SP1: outstanding = {A(t+1)x4, B(t+2)x4} (older drained by
// t-1's wait) -> vmcnt(4) leaves exactly B(t+2) => A(t+1),B(t+1) landed for
// this wave; SP1-end barrier publishes for ALL waves (same proof as R8/R9).
// Overwrite safety: B(t) ds_reads consumed by SP0 MFMAs (compiler lgkm waits)
// before SP0-end barrier; stageB(t+2) issues after it. A(t) rows4-7 retire
// before SP1-end barrier; stageA(t+2) issues at t+1.SP0.
#define BM 256
#define BN 256
#define BK 64
#define NT (C_DIM / BK)                      // 8
#define NBX (XLR / BN)                       // 24
#define NWG ((N_NODES / BM) * NBX)           // 768

__global__ __launch_bounds__(512, 2) void k_gemm_bf16(
    const bf16_t* __restrict__ A,
    const bf16_t* __restrict__ BT,
    const float*  __restrict__ Wl,
    const float*  __restrict__ Wr,
    const float*  __restrict__ coord,
    bf16_t* __restrict__ out)
{
    __shared__ __align__(1024) char smem[131072];   // A: 64KB  B: 64KB
    char* sA = smem;
    char* sB = smem + 65536;

    const int tid  = threadIdx.x;
    const int wave = tid >> 6;
    const int lane = tid & 63;
    const int wm   = wave >> 2;     // 0..1
    const int wn   = wave & 3;      // 0..3

    int bid = blockIdx.y * gridDim.x + blockIdx.x;
    bid = (bid & 7) * (NWG / 8) + (bid >> 3);
    const int rowBase = (bid / NBX) * BM;
    const int colBase = (bid % NBX) * BN;

    const int rtid = tid >> 3;
    const int csw  = ((tid & 7) * 8) ^ (((tid >> 3) & 7) << 3);
    const bf16_t* pA = A  + (size_t)(rowBase + rtid) * C_DIM + csw;
    const bf16_t* pB = BT + (size_t)(colBase + rtid) * C_DIM + csw;

    auto stageA = [&](int t, int h) {
        char* l = sA + ((t & 1) << 15) + (h << 14) + (wave << 10);
        const bf16_t* g = pA + (size_t)(h * 128) * C_DIM + t * BK;
        gload_lds16(g,              l);
        gload_lds16(g + 64 * C_DIM, l + 8192);
    };
    auto stageB = [&](int t, int h) {
        char* l = sB + ((t & 1) << 15) + (h << 14) + (wave << 10);
        const bf16_t* g = pB + (size_t)(h * 128) * C_DIM + t * BK;
        gload_lds16(g,              l);
        gload_lds16(g + 64 * C_DIM, l + 8192);
    };

    // prologue: tile0 complete + tile1 B-halves (12 loads)
    stageB(0, 0); stageB(0, 1); stageA(0, 0); stageA(0, 1);
    stageB(1, 0); stageB(1, 1);
    __builtin_amdgcn_sched_barrier(0);
    asm volatile("s_waitcnt vmcnt(4)" ::: "memory");   // tile0's 8 loads landed (own)
    __builtin_amdgcn_sched_barrier(0);
    asm volatile("s_barrier" ::: "memory");            // -> landed for ALL waves
    __builtin_amdgcn_sched_barrier(0);

    const int kb  = (lane >> 4) << 4;
    const int sw  = (lane & 7) << 4;
    const int xt0 = kb ^ sw;
    const int xt1 = (64 | kb) ^ sw;
    const int aRowOff = (wm * 128 + (lane & 15)) * 128;
    const int bRowOff = (wn * 64  + (lane & 15)) * 128;

    f32x4 acc[8][4] = {};

    #pragma unroll 2
    for (int t = 0; t < NT; ++t) {
        const char* aP = sA + ((t & 1) << 15) + aRowOff;
        const char* bP = sB + ((t & 1) << 15) + bRowOff;
        bf16x8 bfv[4][2];
        bf16x8 af[4][2];   // [row-frag][ks]

        // ===== SP0: stage A(t+1); read A rows0-3 + B; MFMA acc0-3 (32)
        if (t + 1 < NT) { stageA(t + 1, 0); stageA(t + 1, 1); }
        #pragma unroll
        for (int mf = 0; mf < 4; ++mf) {
            af[mf][0] = *(const bf16x8*)(aP + mf*2048 + xt0);
            af[mf][1] = *(const bf16x8*)(aP + mf*2048 + xt1);
        }
        #pragma unroll
        for (int nf = 0; nf < 4; ++nf) {
            bfv[nf][0] = *(const bf16x8*)(bP + nf * 2048 + xt0);
            bfv[nf][1] = *(const bf16x8*)(bP + nf * 2048 + xt1);
        }
        __builtin_amdgcn_s_setprio(1);
        #pragma unroll
        for (int nf = 0; nf < 4; ++nf)
            #pragma unroll
            for (int mf = 0; mf < 4; ++mf)
                acc[mf][nf] = __builtin_amdgcn_mfma_f32_16x16x32_bf16(af[mf][0], bfv[nf][0], acc[mf][nf], 0, 0, 0);
        #pragma unroll
        for (int nf = 0; nf < 4; ++nf)
            #pragma unroll
            for (int mf = 0; mf < 4; ++mf)
                acc[mf][nf] = __builtin_amdgcn_mfma_f32_16x16x32_bf16(af[mf][1], bfv[nf][1], acc[mf][nf], 0, 0, 0);
        __builtin_amdgcn_s_setprio(0);
        __builtin_amdgcn_sched_barrier(0);
        asm volatile("s_barrier" ::: "memory");
        __builtin_amdgcn_sched_barrier(0);

        // ===== SP1: stage B(t+2); read A rows4-7; MFMA acc4-7 (32); vmcnt; barrier
        if (t + 2 < NT) { stageB(t + 2, 0); stageB(t + 2, 1); }
        #pragma unroll
        for (int mf = 0; mf < 4; ++mf) {
            af[mf][0] = *(const bf16x8*)(aP + (4 + mf)*2048 + xt0);
            af[mf][1] = *(const bf16x8*)(aP + (4 + mf)*2048 + xt1);
        }
        __builtin_amdgcn_s_setprio(1);
        #pragma unroll
        for (int nf = 0; nf < 4; ++nf)
            #pragma unroll
            for (int mf = 0; mf < 4; ++mf)
                acc[4 + mf][nf] = __builtin_amdgcn_mfma_f32_16x16x32_bf16(af[mf][0], bfv[nf][0], acc[4 + mf][nf], 0, 0, 0);
        #pragma unroll
        for (int nf = 0; nf < 4; ++nf)
            #pragma unroll
            for (int mf = 0; mf < 4; ++mf)
                acc[4 + mf][nf] = __builtin_amdgcn_mfma_f32_16x16x32_bf16(af[mf][1], bfv[nf][1], acc[4 + mf][nf], 0, 0, 0);
        __builtin_amdgcn_s_setprio(0);
        __builtin_amdgcn_sched_barrier(0);
        if (t < NT - 2)       asm volatile("s_waitcnt vmcnt(4)" ::: "memory");
        else if (t == NT - 2) asm volatile("s_waitcnt vmcnt(0)" ::: "memory");
        __builtin_amdgcn_sched_barrier(0);
        asm volatile("s_barrier" ::: "memory");   // publishes tile t+1
        __builtin_amdgcn_sched_barrier(0);
    }

    // ---- epilogue: fused coord contribution (unchanged)
    const float* Wtop = (colBase < HC) ? Wl : Wr;
    const int coff = (colBase < HC) ? 0 : HC;
    const int ccol  = lane & 15;
    const int crow4 = (lane >> 4) * 4;

    float wv0[4], wv1[4];
    #pragma unroll
    for (int nf = 0; nf < 4; ++nf) {
        int wcol = colBase + wn*64 + nf*16 + ccol - coff;
        wv0[nf] = Wtop[wcol];
        wv1[nf] = Wtop[HC + wcol];
    }
    #pragma unroll
    for (int mf = 0; mf < 8; ++mf) {
        #pragma unroll
        for (int r = 0; r < 4; ++r) {
            int row = rowBase + wm*128 + mf*16 + crow4 + r;
            float c0 = coord[row*2 + 0], c1 = coord[row*2 + 1];
            size_t rb = (size_t)row * XLR;
            #pragma unroll
            for (int nf = 0; nf < 4; ++nf) {
                int col = colBase + wn*64 + nf*16 + ccol;
                out[rb + col] = (bf16_t)(acc[mf][nf][r] + c0 * wv0[nf] + c1 * wv1[nf]);
            }
        }
    }
}

// ---------------- fused attention — R1 dataflow + R10 DPP butterfly (kept)
#define MAX_DEG 128
__global__ __launch_bounds__(384, 8) void k_attn_agg(
    const bf16_t* __restrict__ xlr,
    const int* __restrict__ row_ptr, const int* __restrict__ csr_src,
    const float* __restrict__ att,
    const float* __restrict__ gat_bias, const float* __restrict__ W_coord,
    const float* __restrict__ b_coord, const float* __restrict__ coord_in,
    bf16_t* __restrict__ hidden, float* __restrict__ coord_out)
{
    int n = blockIdx.x;
    int tid = threadIdx.x;
    int h = tid >> 6, lane = tid & 63;
    __shared__ int   s_src[MAX_DEG];
    __shared__ float s_acc[HC];        // 12 KB
    __shared__ float s_red[12];

    int beg = row_ptr[n];
    int deg = min(row_ptr[n + 1] - beg, MAX_DEG);
    for (int j = tid; j < deg; j += 384) s_src[j] = csr_src[beg + j];
    __syncthreads();

    size_t off = (size_t)h * C_DIM + lane * 8;
    bf16x8 xrv = *(const bf16x8*)(xlr + (size_t)n * XLR + HC + off);
    f32x2 xr2[4], at2[4], ac2[4] = {};
    #pragma unroll
    for (int i = 0; i < 4; ++i) {
        xr2[i] = f32x2{(float)xrv[2*i], (float)xrv[2*i+1]};
        at2[i] = f32x2{att[off + 2*i], att[off + 2*i + 1]};
    }

    float l = 0.f;
    int j = 0;
    for (; j + 2 <= deg; j += 2) {
        bf16x8 xa = *(const bf16x8*)(xlr + (size_t)s_src[j]     * XLR + off);
        bf16x8 xb = *(const bf16x8*)(xlr + (size_t)s_src[j + 1] * XLR + off);
        f32x2 xla[4], xlb[4];
        #pragma unroll
        for (int i = 0; i < 4; ++i) {
            xla[i] = f32x2{(float)xa[2*i], (float)xa[2*i+1]};
            xlb[i] = f32x2{(float)xb[2*i], (float)xb[2*i+1]};
        }
        f32x2 sa = {0.f, 0.f}, sb = {0.f, 0.f};
        #pragma unroll
        for (int i = 0; i < 4; ++i) {
            f32x2 va = xla[i] + xr2[i];
            f32x2 vb = xlb[i] + xr2[i];
            sa += __builtin_elementwise_max(va, va * LRELU_SLOPE) * at2[i];
            sb += __builtin_elementwise_max(vb, vb * LRELU_SLOPE) * at2[i];
        }
        float suma = bfly_add64(sa.x + sa.y);
        float sumb = bfly_add64(sb.x + sb.y);
        float aa = __expf(suma), ab = __expf(sumb);
        l += aa + ab;
        #pragma unroll
        for (int i = 0; i < 4; ++i) ac2[i] += aa * xla[i] + ab * xlb[i];
    }
    if (j < deg) {
        bf16x8 xa = *(const bf16x8*)(xlr + (size_t)s_src[j] * XLR + off);
        f32x2 xla[4];
        #pragma unroll
        for (int i = 0; i < 4; ++i) xla[i] = f32x2{(float)xa[2*i], (float)xa[2*i+1]};
        f32x2 sa = {0.f, 0.f};
        #pragma unroll
        for (int i = 0; i < 4; ++i) {
            f32x2 va = xla[i] + xr2[i];
            sa += __builtin_elementwise_max(va, va * LRELU_SLOPE) * at2[i];
        }
        float suma = bfly_add64(sa.x + sa.y);
        float aa = __expf(suma);
        l += aa;
        #pragma unroll
        for (int i = 0; i < 4; ++i) ac2[i] += aa * xla[i];
    }

    float invl = 1.f / (l + 1e-16f) * (1.f / 6.f);   // fold head-mean
    #pragma unroll
    for (int i = 0; i < 4; ++i) {
        s_acc[off + 2*i]     = ac2[i].x * invl;
        s_acc[off + 2*i + 1] = ac2[i].y * invl;
    }
    __syncthreads();

    float p0 = 0.f, p1 = 0.f;
    for (int c = tid; c < C_DIM; c += 384) {
        float s = 0.f;
        #pragma unroll
        for (int hh = 0; hh < H_HEADS; ++hh) s += s_acc[hh * C_DIM + c];
        float hv = selu_f(s + gat_bias[c]);
        hidden[n * C_DIM + c] = (bf16_t)hv;
        p0 = fmaf(hv, W_coord[c * 2 + 0], p0);
        p1 = fmaf(hv, W_coord[c * 2 + 1], p1);
    }
    #pragma unroll
    for (int o = 32; o > 0; o >>= 1) { p0 += __shfl_down(p0, o); p1 += __shfl_down(p1, o); }
    if (lane == 0) { s_red[h * 2] = p0; s_red[h * 2 + 1] = p1; }
    __syncthreads();
    if (tid == 0) {
        float o0 = b_coord[0], o1 = b_coord[1];
        #pragma unroll
        for (int w = 0; w < H_HEADS; ++w) { o0 += s_red[w * 2]; o1 += s_red[w * 2 + 1]; }
        float cx = coord_in[n * 2 + 0], cy = coord_in[n * 2 + 1];
        float ox = (cx == 0.0f) ? 0.f : ((cx == 1.0f) ? 1.f : o0);
        float oy = (cy == 1.0f) ? 1.f : ((cy == 0.0f) ? 0.f : o1);
        coord_out[n * 2 + 0] = ox;
        coord_out[n * 2 + 1] = oy;
    }
}

extern "C" void kernel_launch(void* const* d_in, const int* in_sizes, int n_in,
                              void* d_out, int out_size, void* d_ws, size_t ws_size,
                              hipStream_t stream)
{
    const float* x       = (const float*)d_in[0];
    const float* lf      = (const float*)d_in[1];
    const float* cf      = (const float*)d_in[2];
    const float* W_lin   = (const float*)d_in[3];
    const float* b_lin   = (const float*)d_in[4];
    const float* Wl      = (const float*)d_in[5];
    const float* Wr      = (const float*)d_in[6];
    const float* att     = (const float*)d_in[7];
    const float* gbias   = (const float*)d_in[8];
    const float* W_coord = (const float*)d_in[9];
    const float* b_coord = (const float*)d_in[10];
    const int*   ei      = (const int*)d_in[11];

    char* w = (char*)d_ws;
    auto alloc = [&](size_t bytes) { char* p = w; w += (bytes + 255) & ~255ull; return p; };
    bf16_t*   hidden  = (bf16_t*)alloc((size_t)N_NODES * C_DIM * 2);
    bf16_t*   WT      = (bf16_t*)alloc((size_t)XLR * C_DIM * 2);
    bf16_t*   xlr     = (bf16_t*)alloc((size_t)N_NODES * XLR * 2);
    int*      counts  = (int*)alloc((size_t)N_NODES * 4);
    int*      row_ptr = (int*)alloc((size_t)(N_NODES + 1) * 4);
    int*      cursor  = (int*)alloc((size_t)N_NODES * 4);
    int*      csr_src = (int*)alloc((size_t)NUM_EDGES * 4);
    float*    cA      = (float*)alloc((size_t)N_NODES * 2 * 4);
    float*    cB      = (float*)alloc((size_t)N_NODES * 2 * 4);

    hipMemsetAsync(counts, 0, (size_t)N_NODES * 4, stream);
    k_hidden0<<<N_NODES / 4, 512, 0, stream>>>(x, lf, cf, W_lin, b_lin, hidden, cA);
    {
        dim3 tg(HC / 32, C_DIM / 32);
        k_wt_transpose<<<tg, 256, 0, stream>>>(Wl, WT);
        k_wt_transpose<<<tg, 256, 0, stream>>>(Wr, WT + (size_t)HC * C_DIM);
    }
    k_hist<<<(NUM_EDGES + 255) / 256, 256, 0, stream>>>(ei, counts);
    k_scan<<<1, 256, 0, stream>>>(counts, row_ptr, cursor);
    k_scatter<<<(NUM_EDGES + 255) / 256, 256, 0, stream>>>(ei, cursor, csr_src);

    float* cin = cA;
    for (int it = 0; it < 3; ++it) {
        float* cout = (it == 2) ? (float*)d_out : ((it == 0) ? cB : cA);
        dim3 g(NBX, N_NODES / BM);
        k_gemm_bf16<<<g, 512, 0, stream>>>(hidden, WT, Wl, Wr, cin, xlr);
        k_attn_agg<<<N_NODES, 384, 0, stream>>>(xlr, row_ptr, csr_src, att,
                                                gbias, W_coord, b_coord, cin, hidden, cout);
        cin = cout;
    }
}